// Round 4
// baseline (4328.089 us; speedup 1.0000x reference)
//
#include <hip/hip_runtime.h>
#include <cstdint>
#include <cstddef>

typedef unsigned short u16;
typedef unsigned int u32;

typedef short short8 __attribute__((ext_vector_type(8)));
typedef float floatx4 __attribute__((ext_vector_type(4)));

// Problem constants: B=32, T=512, D=256, H=256, 4H=1024, C=32
// Workspace layout (bytes)
#define O_EMB    0ull                 // emb bf16 [16384][256]
#define O_XG     8388608ull           // xgT bf16 [2][512 t][1024 n][32 b]
#define O_HS     75497472ull          // hs bf16 [2][16384][256]
#define O_LOGITS 92340224ull          // logits f32 [16384][32]  (2.1 MB region)
//   overlay (dead before k4): WhT bf16 [2][1024][256] @ O_LOGITS (1 MB)
//   overlay: exch u32 [2 dir][2 half][2 parity][32][128] @ O_LOGITS+1048576 (128 KB)
#define O_WHT    O_LOGITS
#define O_EXCH   (O_LOGITS + 1048576ull)
#define O_WIT    94437504ull          // WiT bf16 [2][1024][256]
#define O_OUTW   95486080ull          // outW bf16 [512][32]
#define WS_NEED  95518848ull

__device__ __forceinline__ u16 f2bf(float x) {
    u32 u = __float_as_uint(x);
    u += 0x7fffu + ((u >> 16) & 1u);
    return (u16)(u >> 16);
}
__device__ __forceinline__ float bf2f(u16 v) { return __uint_as_float(((u32)v) << 16); }
__device__ __forceinline__ float sigm(float x) { return 1.0f / (1.0f + __expf(-x)); }
__device__ __forceinline__ float tanh_f(float x) {
    x = fminf(30.0f, fmaxf(-30.0f, x));
    float e = __expf(-2.0f * x);
    return (1.0f - e) / (1.0f + e);
}

// ---------------- K0: tiled transposes Wi->WiT, Wh->WhT (bf16 [n][k]); outW -> bf16
__global__ __launch_bounds__(256) void k0_prep(const float* __restrict__ Wi_f, const float* __restrict__ Wi_b,
                                               const float* __restrict__ Wh_f, const float* __restrict__ Wh_b,
                                               const float* __restrict__ out_W,
                                               u16* __restrict__ WiT, u16* __restrict__ WhT,
                                               u16* __restrict__ outWb) {
    if (blockIdx.z == 4) {
        int id = (blockIdx.y * 16 + blockIdx.x) * 256 + threadIdx.x;  // < 16384
        outWb[id] = f2bf(out_W[id]);
        return;
    }
    int z = blockIdx.z;
    const float* src = (z == 0) ? Wi_f : (z == 1) ? Wi_b : (z == 2) ? Wh_f : Wh_b;
    u16* dst = (z == 0) ? WiT : (z == 1) ? (WiT + 262144) : (z == 2) ? WhT : (WhT + 262144);
    __shared__ float lt[64][68];
    int r0 = blockIdx.y * 64;   // k rows
    int c0 = blockIdx.x * 64;   // n cols
    int cc = threadIdx.x & 63, rr = threadIdx.x >> 6;
#pragma unroll
    for (int i = 0; i < 16; ++i) {
        int r = rr + i * 4;
        lt[cc][r] = src[(size_t)(r0 + r) * 1024 + c0 + cc];
    }
    __syncthreads();
#pragma unroll
    for (int i = 0; i < 16; ++i) {
        int n = rr + i * 4;
        dst[(size_t)(c0 + n) * 256 + r0 + cc] = f2bf(lt[n][cc]);
    }
}

// ---------------- K1: embedding gather -> emb bf16 [r=t*32+b][256] -----------------
__global__ __launch_bounds__(256) void k1_embed(const int* __restrict__ chars, const int* __restrict__ bigrams,
                                                const float* __restrict__ ct, const float* __restrict__ bt,
                                                u16* __restrict__ emb) {
    int idx = blockIdx.x * 256 + threadIdx.x;  // grid 8192*256 = 2097152 = 16384*128
    int r = idx >> 7;
    int p2 = (idx & 127) << 1;
    int t = r >> 5, b = r & 31;
    const float* src;
    if (p2 < 128) src = ct + (size_t)chars[b * 512 + t] * 128 + p2;
    else          src = bt + (size_t)bigrams[b * 512 + t] * 128 + (p2 - 128);
    float2 v = *(const float2*)(const void*)src;
    u32 pk = (u32)f2bf(v.x) | ((u32)f2bf(v.y) << 16);
    *(u32*)(void*)(emb + (size_t)r * 256 + p2) = pk;
}

// ---------------- K2: xgT[d][t][n][b] = (emb @ Wi_d + b_d)^T  (bf16 MFMA) ----------
__global__ __launch_bounds__(256) void k2_gemm(const u16* __restrict__ emb, const u16* __restrict__ WiT,
                                               const float* __restrict__ b_f, const float* __restrict__ b_b,
                                               u16* __restrict__ xgT) {
    int mbase = blockIdx.x * 64;    // 64 rows = 2 t-values x 32 b
    int nbase = blockIdx.y * 64;
    int d = blockIdx.z;
    const u16* Bt = WiT + (size_t)d * 262144;
    const float* bias = d ? b_b : b_f;
    u16* xgd = xgT + (size_t)d * 16777216ull;
    __shared__ u16 ctT[64][72];     // [n_local][row_local], pitch 72
    int tid = threadIdx.x;
    int wv = tid >> 6, l = tid & 63, lm = l & 15, lq = l >> 4;
    floatx4 acc[4] = {{0,0,0,0},{0,0,0,0},{0,0,0,0},{0,0,0,0}};
    int arow = mbase + wv * 16 + lm;
#pragma unroll
    for (int kc = 0; kc < 8; ++kc) {
        int k0 = kc * 32 + lq * 8;
        short8 a = *(const short8*)(const void*)(emb + (size_t)arow * 256 + k0);
#pragma unroll
        for (int nt = 0; nt < 4; ++nt) {
            short8 bb = *(const short8*)(const void*)(Bt + (size_t)(nbase + nt * 16 + lm) * 256 + k0);
            acc[nt] = __builtin_amdgcn_mfma_f32_16x16x32_bf16(a, bb, acc[nt], 0, 0, 0);
        }
    }
#pragma unroll
    for (int nt = 0; nt < 4; ++nt) {
        int nl = nt * 16 + lm;
        float bv = bias[nbase + nl];
#pragma unroll
        for (int r = 0; r < 4; ++r) {
            int rl = wv * 16 + lq * 4 + r;
            ctT[nl][rl] = f2bf(acc[nt][r] + bv);
        }
    }
    __syncthreads();
    // write out transposed: xgT[t][n][b], 16 u16 per thread
    int th = tid & 1, seg = tid >> 1;         // 128 segs: (t_loc, nn)
    int tl = seg >> 6, nn = seg & 63;
    int t0 = mbase >> 5;
    uint4 o0 = *(const uint4*)(const void*)&ctT[nn][tl * 32 + th * 16];
    uint4 o1 = *(const uint4*)(const void*)&ctT[nn][tl * 32 + th * 16 + 8];
    u16* dst = xgd + (size_t)(t0 + tl) * 32768 + (size_t)(nbase + nn) * 32 + th * 16;
    *(uint4*)(void*)dst = o0;
    *(uint4*)(void*)(dst + 8) = o1;
}

// ---------------- K3: BiLSTM recurrence, 4 blocks (dir x half), 512 threads -------
// Each block owns h dims [d0,d0+128); Wh slice entirely in REGISTERS (32 B-frags =
// 128 VGPR). Own-half h in LDS (dbuf); peer half exchanged via tagged u32 words
// (bf16 h | step<<16) with relaxed agent atomics -- no flags, no fences. Cooperative
// poll+stage of the peer block into LDS. k order permuted: own dims = kc 0..3.
__global__ __launch_bounds__(512, 2) void k3_lstm(const u16* __restrict__ xgT, const u16* __restrict__ WhT,
                                                  const int* __restrict__ seq_len,
                                                  u32* __restrict__ exch, u16* __restrict__ hs) {
    int bid = blockIdx.x;        // 0..3
    int dir = bid >> 1;
    int half = bid & 1;
    int d0 = half << 7;
    const u16* xgd = xgT + (size_t)dir * 16777216ull;
    u16* hsd = hs + (size_t)dir * 4194304ull;
    const u16* WhTd = WhT + (size_t)dir * 262144ull;
    u32* ex_w = exch + ((size_t)(dir * 2 + half) * 2) * 4096;          // my region [2 parity][4096]
    const u32* ex_r = exch + ((size_t)(dir * 2 + (half ^ 1)) * 2) * 4096;  // peer region

    __shared__ u16 hb[2][32][136];   // own h, double-buffered, padded pitch
    __shared__ u16 hp[32][136];      // staged peer h

    int tid = threadIdx.x;
    int wv = tid >> 6;               // dim-group g: 0..7 (local dims g*16..+16)
    int l = tid & 63, lm = l & 15, lq = l >> 4;

    // ---- stage Wh fragments into registers: bfr[gate][kc] ----
    short8 bfr[4][8];
#pragma unroll
    for (int q = 0; q < 4; ++q) {
        int n = q * 256 + d0 + wv * 16 + lm;
#pragma unroll
        for (int kc = 0; kc < 8; ++kc) {
            int kappa = kc * 32 + lq * 8;
            int absd = (kappa + d0) & 255;
            bfr[q][kc] = *(const short8*)(const void*)(WhTd + (size_t)n * 256 + absd);
        }
    }
    int Lr[8];
#pragma unroll
    for (int mt = 0; mt < 2; ++mt)
#pragma unroll
        for (int r = 0; r < 4; ++r)
            Lr[mt * 4 + r] = seq_len[mt * 16 + lq * 4 + r];
    float cst[8] = {0, 0, 0, 0, 0, 0, 0, 0};
    int prow = tid >> 4;             // peer-stage: row, col base
    int pcol = (tid & 15) * 8;

    for (int s = 0; s < 512; ++s) {
        int t = dir ? (511 - s) : s;
        if (s > 0) {
            // cooperative poll of peer's tagged words (8 per thread), strip, stage to LDS
            const u32* pb = ex_r + (size_t)(s & 1) * 4096 + tid * 8;
            u32 v[8];
            for (;;) {
                bool ok = true;
#pragma unroll
                for (int i = 0; i < 8; ++i) {
                    v[i] = __hip_atomic_load(pb + i, __ATOMIC_RELAXED, __HIP_MEMORY_SCOPE_AGENT);
                    ok = ok && ((v[i] >> 16) == (u32)s);
                }
                if (ok) break;
            }
            u32 pk[4];
#pragma unroll
            for (int i = 0; i < 4; ++i) pk[i] = (v[2 * i] & 0xffffu) | (v[2 * i + 1] << 16);
            *(uint4*)(void*)&hp[prow][pcol] = *(uint4*)(void*)pk;
        }
        __syncthreads();   // bar1: peer staged; own hb[s&1] from last step visible

        // xg loads (transposed layout): per (gate, mtile) 4 bf16 contiguous
        u32 xv[4][2][2];
#pragma unroll
        for (int q = 0; q < 4; ++q)
#pragma unroll
            for (int mt = 0; mt < 2; ++mt) {
                const u16* p = xgd + (size_t)t * 32768 + (size_t)(q * 256 + d0 + wv * 16 + lm) * 32 + mt * 16 + lq * 4;
                uint2 u = *(const uint2*)(const void*)p;
                xv[q][mt][0] = u.x; xv[q][mt][1] = u.y;
            }

        floatx4 acc[4][2];
#pragma unroll
        for (int q = 0; q < 4; ++q) { acc[q][0] = (floatx4){0,0,0,0}; acc[q][1] = (floatx4){0,0,0,0}; }
        if (s > 0) {
#pragma unroll
            for (int kc = 0; kc < 8; ++kc) {
                int ko = ((kc & 3) * 32) + lq * 8;
                short8 a0, a1;
                if (kc < 4) {
                    a0 = *(const short8*)(const void*)&hb[s & 1][lm][ko];
                    a1 = *(const short8*)(const void*)&hb[s & 1][16 + lm][ko];
                } else {
                    a0 = *(const short8*)(const void*)&hp[lm][ko];
                    a1 = *(const short8*)(const void*)&hp[16 + lm][ko];
                }
#pragma unroll
                for (int q = 0; q < 4; ++q) {
                    acc[q][0] = __builtin_amdgcn_mfma_f32_16x16x32_bf16(a0, bfr[q][kc], acc[q][0], 0, 0, 0);
                    acc[q][1] = __builtin_amdgcn_mfma_f32_16x16x32_bf16(a1, bfr[q][kc], acc[q][1], 0, 0, 0);
                }
            }
        }
        // gates + cell update + publish
        u32 tagp = (u32)(s + 1) << 16;
        u32* exo = ex_w + (size_t)((s + 1) & 1) * 4096;
#pragma unroll
        for (int mt = 0; mt < 2; ++mt)
#pragma unroll
            for (int r = 0; r < 4; ++r) {
                int ci = mt * 4 + r;
                int sh = (r & 1) * 16, wi = r >> 1;
                float gi = acc[0][mt][r] + bf2f((u16)(xv[0][mt][wi] >> sh));
                float gf = acc[1][mt][r] + bf2f((u16)(xv[1][mt][wi] >> sh));
                float gg = acc[2][mt][r] + bf2f((u16)(xv[2][mt][wi] >> sh));
                float go = acc[3][mt][r] + bf2f((u16)(xv[3][mt][wi] >> sh));
                float cn = sigm(gf) * cst[ci] + sigm(gi) * tanh_f(gg);
                float hn = sigm(go) * tanh_f(cn);
                if (dir && t >= Lr[ci]) { cn = 0.0f; hn = 0.0f; }   // backward masked prefix
                cst[ci] = cn;
                int row = mt * 16 + lq * 4 + r;
                int col = wv * 16 + lm;
                u16 hb16 = f2bf(hn);
                hb[(s + 1) & 1][row][col] = hb16;
                __hip_atomic_store(exo + row * 128 + col, (u32)hb16 | tagp,
                                   __ATOMIC_RELAXED, __HIP_MEMORY_SCOPE_AGENT);
                hsd[(size_t)(t * 32 + row) * 256 + d0 + col] = hb16;
            }
        __syncthreads();   // bar2: hb/hp write-read separation across steps
    }
}

// ---------------- K4: logits = log_softmax([hf;hb] @ out_W + out_b) ---------------
__global__ __launch_bounds__(256) void k4_proj(const u16* __restrict__ hs, const u16* __restrict__ outWb,
                                               const float* __restrict__ out_b, float* __restrict__ logits) {
    int r = blockIdx.x * 8 + (threadIdx.x >> 5);
    int n = threadIdx.x & 31;
    const u16* hf = hs + (size_t)r * 256;
    const u16* hbk = hs + 4194304ull + (size_t)r * 256;
    float acc = out_b[n];
#pragma unroll 4
    for (int k = 0; k < 256; k += 2) {
        u32 hv = *(const u32*)(const void*)(hf + k);
        acc += bf2f((u16)hv) * bf2f(outWb[k * 32 + n]);
        acc += bf2f((u16)(hv >> 16)) * bf2f(outWb[(k + 1) * 32 + n]);
    }
#pragma unroll 4
    for (int k = 0; k < 256; k += 2) {
        u32 hv = *(const u32*)(const void*)(hbk + k);
        acc += bf2f((u16)hv) * bf2f(outWb[(256 + k) * 32 + n]);
        acc += bf2f((u16)(hv >> 16)) * bf2f(outWb[(257 + k) * 32 + n]);
    }
    float m = acc;
#pragma unroll
    for (int d2 = 16; d2 >= 1; d2 >>= 1) m = fmaxf(m, __shfl_xor(m, d2, 32));
    float s = __expf(acc - m);
#pragma unroll
    for (int d2 = 16; d2 >= 1; d2 >>= 1) s += __shfl_xor(s, d2, 32);
    logits[(size_t)r * 32 + n] = acc - m - __logf(s);
}

// ---------------- K5: CRF forward + gold score -> out[b] --------------------------
// Stage this sample's logits to LDS (bf16), then single-wave register recursion.
__global__ __launch_bounds__(256) void k5_crf(const float* __restrict__ logits, const int* __restrict__ target,
                                              const int* __restrict__ seq_len, const float* __restrict__ trans,
                                              const float* __restrict__ start_trans, const float* __restrict__ end_trans,
                                              float* __restrict__ out) {
    int b = blockIdx.x;
    int tid = threadIdx.x;
    int L = seq_len[b];
    __shared__ u16 sl[16384];      // [t][c] bf16
    __shared__ float red[4];
    __shared__ float goldsh;
#pragma unroll 4
    for (int it = 0; it < 64; ++it) {
        int idx = it * 256 + tid;
        sl[idx] = f2bf(logits[((size_t)(idx >> 5) * 32 + b) * 32 + (idx & 31)]);
    }
    __syncthreads();
    // gold path score
    float part = 0.0f;
    for (int t = tid; t < 512; t += 256) {
        if (t < L) {
            int tg = target[b * 512 + t];
            part += bf2f(sl[t * 32 + tg]);
            if (t >= 1) part += trans[target[b * 512 + t - 1] * 32 + tg];
        }
    }
#pragma unroll
    for (int d2 = 32; d2 >= 1; d2 >>= 1) part += __shfl_xor(part, d2, 64);
    if ((tid & 63) == 0) red[tid >> 6] = part;
    __syncthreads();
    if (tid == 0) {
        goldsh = red[0] + red[1] + red[2] + red[3]
               + start_trans[target[b * 512]] + end_trans[target[b * 512 + L - 1]];
    }
    __syncthreads();
    if (tid >= 64) return;
    int j = tid & 31, h = tid >> 5;    // lanes (h, j): half h covers i in [h*16, h*16+16)
    float tr[16];
#pragma unroll
    for (int i = 0; i < 16; ++i) tr[i] = trans[(h * 16 + i) * 32 + j];
    float alpha = bf2f(sl[j]) + start_trans[j];
    for (int t = 1; t < 512; ++t) {
        float m = -1e30f, vv[16];
#pragma unroll
        for (int i = 0; i < 16; ++i) {
            float ai = __shfl(alpha, h * 16 + i, 64);
            vv[i] = ai + tr[i];
            m = fmaxf(m, vv[i]);
        }
        float ssum = 0.0f;
#pragma unroll
        for (int i = 0; i < 16; ++i) ssum += __expf(vv[i] - m);
        float m2 = __shfl_xor(m, 32, 64);
        float s2 = __shfl_xor(ssum, 32, 64);
        float M = fmaxf(m, m2);
        float stot = ssum * __expf(m - M) + s2 * __expf(m2 - M);
        float nv = bf2f(sl[t * 32 + j]) + M + __logf(stot);
        alpha = (t < L) ? nv : alpha;
    }
    if (h == 0) {
        float v = alpha + end_trans[j];
        float m = v;
#pragma unroll
        for (int d2 = 16; d2 >= 1; d2 >>= 1) m = fmaxf(m, __shfl_xor(m, d2, 32));
        float ss = __expf(v - m);
#pragma unroll
        for (int d2 = 16; d2 >= 1; d2 >>= 1) ss += __shfl_xor(ss, d2, 32);
        if (j == 0) out[b] = m + __logf(ss) - goldsh;
    }
}

extern "C" void kernel_launch(void* const* d_in, const int* in_sizes, int n_in,
                              void* d_out, int out_size, void* d_ws, size_t ws_size,
                              hipStream_t stream) {
    if (ws_size < WS_NEED) return;  // workspace too small: fail cleanly, no OOB
    const int* chars = (const int*)d_in[0];
    const int* bigrams = (const int*)d_in[1];
    const int* seq_len = (const int*)d_in[2];
    const int* target = (const int*)d_in[3];
    const float* char_table = (const float*)d_in[4];
    const float* bigram_table = (const float*)d_in[5];
    const float* Wi_f = (const float*)d_in[6];
    const float* Wh_f = (const float*)d_in[7];
    const float* b_f = (const float*)d_in[8];
    const float* Wi_b = (const float*)d_in[9];
    const float* Wh_b = (const float*)d_in[10];
    const float* b_b = (const float*)d_in[11];
    const float* out_W = (const float*)d_in[12];
    const float* out_b = (const float*)d_in[13];
    const float* trans = (const float*)d_in[14];
    const float* start_trans = (const float*)d_in[15];
    const float* end_trans = (const float*)d_in[16];

    char* ws = (char*)d_ws;
    u16* emb = (u16*)(ws + O_EMB);
    u16* xgT = (u16*)(ws + O_XG);
    u16* hs = (u16*)(ws + O_HS);
    float* logits = (float*)(ws + O_LOGITS);
    u16* WhT = (u16*)(ws + O_WHT);
    u32* exch = (u32*)(ws + O_EXCH);
    u16* WiT = (u16*)(ws + O_WIT);
    u16* outWb = (u16*)(ws + O_OUTW);

    hipLaunchKernelGGL(k0_prep, dim3(16, 4, 5), dim3(256), 0, stream,
                       Wi_f, Wi_b, Wh_f, Wh_b, out_W, WiT, WhT, outWb);
    hipLaunchKernelGGL(k1_embed, dim3(8192), dim3(256), 0, stream, chars, bigrams, char_table, bigram_table, emb);
    hipLaunchKernelGGL(k2_gemm, dim3(256, 16, 2), dim3(256), 0, stream, emb, WiT, b_f, b_b, xgT);
    hipLaunchKernelGGL(k3_lstm, dim3(4), dim3(512), 0, stream, xgT, WhT, seq_len, exch, hs);
    hipLaunchKernelGGL(k4_proj, dim3(2048), dim3(256), 0, stream, hs, outWb, out_b, logits);
    hipLaunchKernelGGL(k5_crf, dim3(32), dim3(256), 0, stream, logits, target, seq_len, trans, start_trans, end_trans,
                       (float*)d_out);
}

// Round 5
// 4040.280 us; speedup vs baseline: 1.0712x; 1.0712x over previous
//
#include <hip/hip_runtime.h>
#include <cstdint>
#include <cstddef>

typedef unsigned short u16;
typedef unsigned int u32;

typedef short short8 __attribute__((ext_vector_type(8)));
typedef float floatx4 __attribute__((ext_vector_type(4)));

// Problem constants: B=32, T=512, D=256, H=256, 4H=1024, C=32
// Workspace layout (bytes)
#define O_EMB    0ull                 // emb bf16 [16384][256]
#define O_XG     8388608ull           // xgT bf16 [2][512 t][1024 n][32 b]
#define O_HS     75497472ull          // hs bf16 [2][16384][256]
#define O_LOGITS 92340224ull          // logits f32 [16384][32]  (2.1 MB region)
//   overlay (dead before k4): WhT bf16 [2][1024][256] @ O_LOGITS (1 MB)
//   overlay: exch u32 [2 dir][2 half][2 parity][32][128] @ O_LOGITS+1048576 (128 KB)
#define O_WHT    O_LOGITS
#define O_EXCH   (O_LOGITS + 1048576ull)
#define O_WIT    94437504ull          // WiT bf16 [2][1024][256]
#define O_OUTW   95486080ull          // outW bf16 [512][32]
#define WS_NEED  95518848ull

__device__ __forceinline__ u16 f2bf(float x) {
    u32 u = __float_as_uint(x);
    u += 0x7fffu + ((u >> 16) & 1u);
    return (u16)(u >> 16);
}
__device__ __forceinline__ float bf2f(u16 v) { return __uint_as_float(((u32)v) << 16); }
__device__ __forceinline__ float sigm(float x) { return 1.0f / (1.0f + __expf(-x)); }
__device__ __forceinline__ float tanh_f(float x) {
    x = fminf(30.0f, fmaxf(-30.0f, x));
    float e = __expf(-2.0f * x);
    return (1.0f - e) / (1.0f + e);
}

// ---------------- K0: tiled transposes Wi->WiT, Wh->WhT (bf16 [n][k]); outW -> bf16
__global__ __launch_bounds__(256) void k0_prep(const float* __restrict__ Wi_f, const float* __restrict__ Wi_b,
                                               const float* __restrict__ Wh_f, const float* __restrict__ Wh_b,
                                               const float* __restrict__ out_W,
                                               u16* __restrict__ WiT, u16* __restrict__ WhT,
                                               u16* __restrict__ outWb) {
    if (blockIdx.z == 4) {
        int id = (blockIdx.y * 16 + blockIdx.x) * 256 + threadIdx.x;  // < 16384
        outWb[id] = f2bf(out_W[id]);
        return;
    }
    int z = blockIdx.z;
    const float* src = (z == 0) ? Wi_f : (z == 1) ? Wi_b : (z == 2) ? Wh_f : Wh_b;
    u16* dst = (z == 0) ? WiT : (z == 1) ? (WiT + 262144) : (z == 2) ? WhT : (WhT + 262144);
    __shared__ float lt[64][68];
    int r0 = blockIdx.y * 64;   // k rows
    int c0 = blockIdx.x * 64;   // n cols
    int cc = threadIdx.x & 63, rr = threadIdx.x >> 6;
#pragma unroll
    for (int i = 0; i < 16; ++i) {
        int r = rr + i * 4;
        lt[cc][r] = src[(size_t)(r0 + r) * 1024 + c0 + cc];
    }
    __syncthreads();
#pragma unroll
    for (int i = 0; i < 16; ++i) {
        int n = rr + i * 4;
        dst[(size_t)(c0 + n) * 256 + r0 + cc] = f2bf(lt[n][cc]);
    }
}

// ---------------- K1: embedding gather -> emb bf16 [r=t*32+b][256] -----------------
__global__ __launch_bounds__(256) void k1_embed(const int* __restrict__ chars, const int* __restrict__ bigrams,
                                                const float* __restrict__ ct, const float* __restrict__ bt,
                                                u16* __restrict__ emb) {
    int idx = blockIdx.x * 256 + threadIdx.x;  // grid 8192*256 = 2097152 = 16384*128
    int r = idx >> 7;
    int p2 = (idx & 127) << 1;
    int t = r >> 5, b = r & 31;
    const float* src;
    if (p2 < 128) src = ct + (size_t)chars[b * 512 + t] * 128 + p2;
    else          src = bt + (size_t)bigrams[b * 512 + t] * 128 + (p2 - 128);
    float2 v = *(const float2*)(const void*)src;
    u32 pk = (u32)f2bf(v.x) | ((u32)f2bf(v.y) << 16);
    *(u32*)(void*)(emb + (size_t)r * 256 + p2) = pk;
}

// ---------------- K2: xgT[d][t][n][b] = (emb @ Wi_d + b_d)^T  (bf16 MFMA) ----------
__global__ __launch_bounds__(256) void k2_gemm(const u16* __restrict__ emb, const u16* __restrict__ WiT,
                                               const float* __restrict__ b_f, const float* __restrict__ b_b,
                                               u16* __restrict__ xgT) {
    int mbase = blockIdx.x * 64;    // 64 rows = 2 t-values x 32 b
    int nbase = blockIdx.y * 64;
    int d = blockIdx.z;
    const u16* Bt = WiT + (size_t)d * 262144;
    const float* bias = d ? b_b : b_f;
    u16* xgd = xgT + (size_t)d * 16777216ull;
    __shared__ u16 ctT[64][72];     // [n_local][row_local], pitch 72
    int tid = threadIdx.x;
    int wv = tid >> 6, l = tid & 63, lm = l & 15, lq = l >> 4;
    floatx4 acc[4] = {{0,0,0,0},{0,0,0,0},{0,0,0,0},{0,0,0,0}};
    int arow = mbase + wv * 16 + lm;
#pragma unroll
    for (int kc = 0; kc < 8; ++kc) {
        int k0 = kc * 32 + lq * 8;
        short8 a = *(const short8*)(const void*)(emb + (size_t)arow * 256 + k0);
#pragma unroll
        for (int nt = 0; nt < 4; ++nt) {
            short8 bb = *(const short8*)(const void*)(Bt + (size_t)(nbase + nt * 16 + lm) * 256 + k0);
            acc[nt] = __builtin_amdgcn_mfma_f32_16x16x32_bf16(a, bb, acc[nt], 0, 0, 0);
        }
    }
#pragma unroll
    for (int nt = 0; nt < 4; ++nt) {
        int nl = nt * 16 + lm;
        float bv = bias[nbase + nl];
#pragma unroll
        for (int r = 0; r < 4; ++r) {
            int rl = wv * 16 + lq * 4 + r;
            ctT[nl][rl] = f2bf(acc[nt][r] + bv);
        }
    }
    __syncthreads();
    // write out transposed: xgT[t][n][b], 16 u16 per thread
    int th = tid & 1, seg = tid >> 1;         // 128 segs: (t_loc, nn)
    int tl = seg >> 6, nn = seg & 63;
    int t0 = mbase >> 5;
    uint4 o0 = *(const uint4*)(const void*)&ctT[nn][tl * 32 + th * 16];
    uint4 o1 = *(const uint4*)(const void*)&ctT[nn][tl * 32 + th * 16 + 8];
    u16* dst = xgd + (size_t)(t0 + tl) * 32768 + (size_t)(nbase + nn) * 32 + th * 16;
    *(uint4*)(void*)dst = o0;
    *(uint4*)(void*)(dst + 8) = o1;
}

// ---------------- K3: BiLSTM recurrence, 4 blocks (dir x half), 512 threads -------
// Each block owns h dims [d0,d0+128); Wh slice entirely in REGISTERS (32 B-frags =
// 128 VGPR). __launch_bounds__(512,1): 256-VGPR budget -- R4's (512,2) capped at 128
// VGPR and spilled bfr to scratch, reloading 512B/thread/step in the MFMA loop (the
// 2x regression). Own-half h in LDS (dbuf); peer half via tagged u32 words
// (bf16 h | step<<16), relaxed agent atomics, no flags/fences. Own-half MFMA runs
// BEFORE the poll (hidden under peer latency); poll has s_sleep backoff so the
// producer's stores aren't starved at L3 by the spin.
__global__ __launch_bounds__(512, 1) void k3_lstm(const u16* __restrict__ xgT, const u16* __restrict__ WhT,
                                                  const int* __restrict__ seq_len,
                                                  u32* __restrict__ exch, u16* __restrict__ hs) {
    int bid = blockIdx.x;        // 0..3
    int dir = bid >> 1;
    int half = bid & 1;
    int d0 = half << 7;
    const u16* xgd = xgT + (size_t)dir * 16777216ull;
    u16* hsd = hs + (size_t)dir * 4194304ull;
    const u16* WhTd = WhT + (size_t)dir * 262144ull;
    u32* ex_w = exch + ((size_t)(dir * 2 + half) * 2) * 4096;          // my region [2 parity][4096]
    const u32* ex_r = exch + ((size_t)(dir * 2 + (half ^ 1)) * 2) * 4096;  // peer region

    __shared__ u16 hb[2][32][136];   // own h, double-buffered, padded pitch
    __shared__ u16 hp[32][136];      // staged peer h

    int tid = threadIdx.x;
    int wv = tid >> 6;               // dim-group g: 0..7 (local dims g*16..+16)
    int l = tid & 63, lm = l & 15, lq = l >> 4;

    // ---- stage Wh fragments into registers: bfr[gate][kc] ----
    short8 bfr[4][8];
#pragma unroll
    for (int q = 0; q < 4; ++q) {
        int n = q * 256 + d0 + wv * 16 + lm;
#pragma unroll
        for (int kc = 0; kc < 8; ++kc) {
            int kappa = kc * 32 + lq * 8;
            int absd = (kappa + d0) & 255;
            bfr[q][kc] = *(const short8*)(const void*)(WhTd + (size_t)n * 256 + absd);
        }
    }
    int Lr[8];
#pragma unroll
    for (int mt = 0; mt < 2; ++mt)
#pragma unroll
        for (int r = 0; r < 4; ++r)
            Lr[mt * 4 + r] = seq_len[mt * 16 + lq * 4 + r];
    float cst[8] = {0, 0, 0, 0, 0, 0, 0, 0};
    int prow = tid >> 4;             // peer-stage: row, col base
    int pcol = (tid & 15) * 8;

    for (int s = 0; s < 512; ++s) {
        int t = dir ? (511 - s) : s;
        // xg loads first (independent of poll & peer): per (gate, mtile) 4 bf16
        u32 xv[4][2][2];
#pragma unroll
        for (int q = 0; q < 4; ++q)
#pragma unroll
            for (int mt = 0; mt < 2; ++mt) {
                const u16* p = xgd + (size_t)t * 32768 + (size_t)(q * 256 + d0 + wv * 16 + lm) * 32 + mt * 16 + lq * 4;
                uint2 u = *(const uint2*)(const void*)p;
                xv[q][mt][0] = u.x; xv[q][mt][1] = u.y;
            }

        floatx4 acc[4][2];
#pragma unroll
        for (int q = 0; q < 4; ++q) { acc[q][0] = (floatx4){0,0,0,0}; acc[q][1] = (floatx4){0,0,0,0}; }

        if (s > 0) {
            // own-half MFMA (kc 0..3) from hb -- runs while peer data is in flight
#pragma unroll
            for (int kc = 0; kc < 4; ++kc) {
                int ko = kc * 32 + lq * 8;
                short8 a0 = *(const short8*)(const void*)&hb[s & 1][lm][ko];
                short8 a1 = *(const short8*)(const void*)&hb[s & 1][16 + lm][ko];
#pragma unroll
                for (int q = 0; q < 4; ++q) {
                    acc[q][0] = __builtin_amdgcn_mfma_f32_16x16x32_bf16(a0, bfr[q][kc], acc[q][0], 0, 0, 0);
                    acc[q][1] = __builtin_amdgcn_mfma_f32_16x16x32_bf16(a1, bfr[q][kc], acc[q][1], 0, 0, 0);
                }
            }
            // cooperative poll of peer's tagged words (8 per thread), strip, stage to LDS
            const u32* pb = ex_r + (size_t)(s & 1) * 4096 + tid * 8;
            u32 v[8];
            for (;;) {
                bool ok = true;
#pragma unroll
                for (int i = 0; i < 8; ++i) {
                    v[i] = __hip_atomic_load(pb + i, __ATOMIC_RELAXED, __HIP_MEMORY_SCOPE_AGENT);
                    ok = ok && ((v[i] >> 16) == (u32)s);
                }
                if (ok) break;
                __builtin_amdgcn_s_sleep(1);   // back off: don't starve producer stores at L3
            }
            u32 pk[4];
#pragma unroll
            for (int i = 0; i < 4; ++i) pk[i] = (v[2 * i] & 0xffffu) | (v[2 * i + 1] << 16);
            *(uint4*)(void*)&hp[prow][pcol] = *(uint4*)(void*)pk;
        }
        __syncthreads();   // bar1: peer staged

        if (s > 0) {
            // peer-half MFMA (kc 4..7) from hp
#pragma unroll
            for (int kc = 4; kc < 8; ++kc) {
                int ko = (kc & 3) * 32 + lq * 8;
                short8 a0 = *(const short8*)(const void*)&hp[lm][ko];
                short8 a1 = *(const short8*)(const void*)&hp[16 + lm][ko];
#pragma unroll
                for (int q = 0; q < 4; ++q) {
                    acc[q][0] = __builtin_amdgcn_mfma_f32_16x16x32_bf16(a0, bfr[q][kc], acc[q][0], 0, 0, 0);
                    acc[q][1] = __builtin_amdgcn_mfma_f32_16x16x32_bf16(a1, bfr[q][kc], acc[q][1], 0, 0, 0);
                }
            }
        }
        // gates + cell update + publish
        u32 tagp = (u32)(s + 1) << 16;
        u32* exo = ex_w + (size_t)((s + 1) & 1) * 4096;
#pragma unroll
        for (int mt = 0; mt < 2; ++mt)
#pragma unroll
            for (int r = 0; r < 4; ++r) {
                int ci = mt * 4 + r;
                int sh = (r & 1) * 16, wi = r >> 1;
                float gi = acc[0][mt][r] + bf2f((u16)(xv[0][mt][wi] >> sh));
                float gf = acc[1][mt][r] + bf2f((u16)(xv[1][mt][wi] >> sh));
                float gg = acc[2][mt][r] + bf2f((u16)(xv[2][mt][wi] >> sh));
                float go = acc[3][mt][r] + bf2f((u16)(xv[3][mt][wi] >> sh));
                float cn = sigm(gf) * cst[ci] + sigm(gi) * tanh_f(gg);
                float hn = sigm(go) * tanh_f(cn);
                if (dir && t >= Lr[ci]) { cn = 0.0f; hn = 0.0f; }   // backward masked prefix
                cst[ci] = cn;
                int row = mt * 16 + lq * 4 + r;
                int col = wv * 16 + lm;
                u16 hb16 = f2bf(hn);
                hb[(s + 1) & 1][row][col] = hb16;
                __hip_atomic_store(exo + row * 128 + col, (u32)hb16 | tagp,
                                   __ATOMIC_RELAXED, __HIP_MEMORY_SCOPE_AGENT);
                hsd[(size_t)(t * 32 + row) * 256 + d0 + col] = hb16;
            }
        __syncthreads();   // bar2: hb/hp write-read separation across steps
    }
}

// ---------------- K4: logits = log_softmax([hf;hb] @ out_W + out_b) ---------------
__global__ __launch_bounds__(256) void k4_proj(const u16* __restrict__ hs, const u16* __restrict__ outWb,
                                               const float* __restrict__ out_b, float* __restrict__ logits) {
    int r = blockIdx.x * 8 + (threadIdx.x >> 5);
    int n = threadIdx.x & 31;
    const u16* hf = hs + (size_t)r * 256;
    const u16* hbk = hs + 4194304ull + (size_t)r * 256;
    float acc = out_b[n];
#pragma unroll 4
    for (int k = 0; k < 256; k += 2) {
        u32 hv = *(const u32*)(const void*)(hf + k);
        acc += bf2f((u16)hv) * bf2f(outWb[k * 32 + n]);
        acc += bf2f((u16)(hv >> 16)) * bf2f(outWb[(k + 1) * 32 + n]);
    }
#pragma unroll 4
    for (int k = 0; k < 256; k += 2) {
        u32 hv = *(const u32*)(const void*)(hbk + k);
        acc += bf2f((u16)hv) * bf2f(outWb[(256 + k) * 32 + n]);
        acc += bf2f((u16)(hv >> 16)) * bf2f(outWb[(257 + k) * 32 + n]);
    }
    float m = acc;
#pragma unroll
    for (int d2 = 16; d2 >= 1; d2 >>= 1) m = fmaxf(m, __shfl_xor(m, d2, 32));
    float s = __expf(acc - m);
#pragma unroll
    for (int d2 = 16; d2 >= 1; d2 >>= 1) s += __shfl_xor(s, d2, 32);
    logits[(size_t)r * 32 + n] = acc - m - __logf(s);
}

// ---------------- K5: CRF forward + gold score -> out[b] --------------------------
// Gold from global f32 logits; single-wave register recursion with prefetched f32
// emissions (no bf16 staging -> full accuracy).
__global__ __launch_bounds__(256) void k5_crf(const float* __restrict__ logits, const int* __restrict__ target,
                                              const int* __restrict__ seq_len, const float* __restrict__ trans,
                                              const float* __restrict__ start_trans, const float* __restrict__ end_trans,
                                              float* __restrict__ out) {
    int b = blockIdx.x;
    int tid = threadIdx.x;
    int L = seq_len[b];
    __shared__ float red[4];
    __shared__ float goldsh;

    // gold path score
    float part = 0.0f;
    for (int t = tid; t < 512; t += 256) {
        if (t < L) {
            int tg = target[b * 512 + t];
            part += logits[((size_t)(t * 32 + b)) * 32 + tg];
            if (t >= 1) part += trans[target[b * 512 + t - 1] * 32 + tg];
        }
    }
#pragma unroll
    for (int d2 = 32; d2 >= 1; d2 >>= 1) part += __shfl_xor(part, d2, 64);
    if ((tid & 63) == 0) red[tid >> 6] = part;
    __syncthreads();
    if (tid == 0) {
        goldsh = red[0] + red[1] + red[2] + red[3]
               + start_trans[target[b * 512]] + end_trans[target[b * 512 + L - 1]];
    }
    __syncthreads();
    if (tid >= 64) return;
    int j = tid & 31, h = tid >> 5;    // lanes (h, j): half h covers i in [h*16, h*16+16)
    float tr[16];
#pragma unroll
    for (int i = 0; i < 16; ++i) tr[i] = trans[(h * 16 + i) * 32 + j];
    float alpha = logits[(size_t)b * 32 + j] + start_trans[j];
    float e_next = logits[((size_t)(32 + b)) * 32 + j];
    for (int t = 1; t < 512; ++t) {
        float e = e_next;
        if (t < 511) e_next = logits[((size_t)((t + 1) * 32 + b)) * 32 + j];
        float m = -1e30f, vv[16];
#pragma unroll
        for (int i = 0; i < 16; ++i) {
            float ai = __shfl(alpha, h * 16 + i, 64);
            vv[i] = ai + tr[i];
            m = fmaxf(m, vv[i]);
        }
        float ssum = 0.0f;
#pragma unroll
        for (int i = 0; i < 16; ++i) ssum += __expf(vv[i] - m);
        float m2 = __shfl_xor(m, 32, 64);
        float s2 = __shfl_xor(ssum, 32, 64);
        float M = fmaxf(m, m2);
        float stot = ssum * __expf(m - M) + s2 * __expf(m2 - M);
        float nv = e + M + __logf(stot);
        alpha = (t < L) ? nv : alpha;
    }
    if (h == 0) {
        float v = alpha + end_trans[j];
        float m = v;
#pragma unroll
        for (int d2 = 16; d2 >= 1; d2 >>= 1) m = fmaxf(m, __shfl_xor(m, d2, 32));
        float ss = __expf(v - m);
#pragma unroll
        for (int d2 = 16; d2 >= 1; d2 >>= 1) ss += __shfl_xor(ss, d2, 32);
        if (j == 0) out[b] = m + __logf(ss) - goldsh;
    }
}

extern "C" void kernel_launch(void* const* d_in, const int* in_sizes, int n_in,
                              void* d_out, int out_size, void* d_ws, size_t ws_size,
                              hipStream_t stream) {
    if (ws_size < WS_NEED) return;  // workspace too small: fail cleanly, no OOB
    const int* chars = (const int*)d_in[0];
    const int* bigrams = (const int*)d_in[1];
    const int* seq_len = (const int*)d_in[2];
    const int* target = (const int*)d_in[3];
    const float* char_table = (const float*)d_in[4];
    const float* bigram_table = (const float*)d_in[5];
    const float* Wi_f = (const float*)d_in[6];
    const float* Wh_f = (const float*)d_in[7];
    const float* b_f = (const float*)d_in[8];
    const float* Wi_b = (const float*)d_in[9];
    const float* Wh_b = (const float*)d_in[10];
    const float* b_b = (const float*)d_in[11];
    const float* out_W = (const float*)d_in[12];
    const float* out_b = (const float*)d_in[13];
    const float* trans = (const float*)d_in[14];
    const float* start_trans = (const float*)d_in[15];
    const float* end_trans = (const float*)d_in[16];

    char* ws = (char*)d_ws;
    u16* emb = (u16*)(ws + O_EMB);
    u16* xgT = (u16*)(ws + O_XG);
    u16* hs = (u16*)(ws + O_HS);
    float* logits = (float*)(ws + O_LOGITS);
    u16* WhT = (u16*)(ws + O_WHT);
    u32* exch = (u32*)(ws + O_EXCH);
    u16* WiT = (u16*)(ws + O_WIT);
    u16* outWb = (u16*)(ws + O_OUTW);

    hipLaunchKernelGGL(k0_prep, dim3(16, 4, 5), dim3(256), 0, stream,
                       Wi_f, Wi_b, Wh_f, Wh_b, out_W, WiT, WhT, outWb);
    hipLaunchKernelGGL(k1_embed, dim3(8192), dim3(256), 0, stream, chars, bigrams, char_table, bigram_table, emb);
    hipLaunchKernelGGL(k2_gemm, dim3(256, 16, 2), dim3(256), 0, stream, emb, WiT, b_f, b_b, xgT);
    hipLaunchKernelGGL(k3_lstm, dim3(4), dim3(512), 0, stream, xgT, WhT, seq_len, exch, hs);
    hipLaunchKernelGGL(k4_proj, dim3(2048), dim3(256), 0, stream, hs, outWb, out_b, logits);
    hipLaunchKernelGGL(k5_crf, dim3(32), dim3(256), 0, stream, logits, target, seq_len, trans, start_trans, end_trans,
                       (float*)d_out);
}